// Round 11
// baseline (32.882 us; speedup 1.0000x reference)
//
#include <hip/hip_runtime.h>
#include <math.h>

#define NB 32
#define NT 128
#define KD 16

typedef float f32x4 __attribute__((ext_vector_type(4)));
typedef short bf16x8 __attribute__((ext_vector_type(8)));
typedef __fp16 f16x2 __attribute__((ext_vector_type(2)));
union U4B8 { uint4 u; bf16x8 h; };
union U4H8 { uint4 u; f16x2 h[4]; };

// LDS byte map (71808 B -> 2 blocks/CU)
#define L_S   0        // f32 [128][17] = 8704 (live whole kernel)
#define L_Q   8704     // f32 [8][68]   = 2176
#define L_PK  10880    // f32 [128][68] = 34816 ; aliased by X/H1/H2 after PV
#define L_PV  45696    // f16 [64][136] = 17408
#define L_P   63104    // f16 [32][136] = 8704  (p~ rows; later head buffer)
#define L_TOT 71808
#define L_X   10880    // bf16 [16][104] = 3328
#define L_H1  14464    // bf16 [16][264] = 8448 (ends 22912)
#define L_H2  22912    // bf16 [16][264] = 8448 (ends 31360 < 45696: Pk dead)

__device__ __forceinline__ unsigned short bf16rne(float f) {
    unsigned u = __float_as_uint(f);
    return (unsigned short)((u + 0x7fffu + ((u >> 16) & 1u)) >> 16);
}
__device__ __forceinline__ unsigned cvt2bf(float a, float b) {
    unsigned r;
    asm("v_cvt_pk_bf16_f32 %0, %1, %2" : "=v"(r) : "v"(a), "v"(b));
    return r;   // lo16 = bf16(a), hi16 = bf16(b)
}
__device__ __forceinline__ void unpack8(uint4 u, float* f) {
    f[0] = __uint_as_float(u.x << 16); f[1] = __uint_as_float(u.x & 0xffff0000u);
    f[2] = __uint_as_float(u.y << 16); f[3] = __uint_as_float(u.y & 0xffff0000u);
    f[4] = __uint_as_float(u.z << 16); f[5] = __uint_as_float(u.z & 0xffff0000u);
    f[6] = __uint_as_float(u.w << 16); f[7] = __uint_as_float(u.w & 0xffff0000u);
}
__device__ __forceinline__ f16x2 pkmax(f16x2 a, f16x2 b) {
    f16x2 d;
    asm("v_pk_max_f16 %0, %1, %2" : "=v"(d) : "v"(a), "v"(b));
    return d;
}
__device__ __forceinline__ unsigned cvt2h(float a, float b) {
    f16x2 t = __builtin_amdgcn_cvt_pkrtz(a, b);
    return *(unsigned*)&t;
}
#if __has_builtin(__builtin_amdgcn_fdot2)
#define FDOT2(a, b, c) __builtin_amdgcn_fdot2((a), (b), (c), false)
#else
#define FDOT2(a, b, c) ((c) + (float)(a)[0] * (float)(b)[0] + (float)(a)[1] * (float)(b)[1])
#endif

__global__ __launch_bounds__(512, 4) void actor_kernel(
    const float* __restrict__ state, const float* __restrict__ eps,
    const float* __restrict__ Wq, const float* __restrict__ bq,
    const float* __restrict__ Wk, const float* __restrict__ bk,
    const float* __restrict__ Wv, const float* __restrict__ bv,
    const float* __restrict__ W1, const float* __restrict__ b1g,
    const float* __restrict__ W2, const float* __restrict__ b2g,
    const float* __restrict__ Wmu, const float* __restrict__ bmu,
    const float* __restrict__ Wls, const float* __restrict__ bls,
    float* __restrict__ out)
{
    __shared__ __align__(16) char sm[L_TOT];
    float* smS  = (float*)(sm + L_S);
    float* smQ  = (float*)(sm + L_Q);
    float* smPk = (float*)(sm + L_PK);

    const int tid = threadIdx.x, w = tid >> 6, lane = tid & 63;
    const int b = blockIdx.x >> 4, tile = blockIdx.x & 15;
    const int iloc = tile * 8 + w;                 // this wave's row in batch
    const int h = lane >> 4, s = lane & 15, h16 = h << 4;
    const int g = h, lr = s;                       // MFMA frag coords
    const int t0 = 2 * w;                          // wave's 2 neuron col-tiles
    const int n0 = w * 32 + lr, n1 = n0 + 16;

    // ---- stage state[b] into LDS f32 [128][17] (512 float4, 1/thread) ----
    {
        float4 v = ((const float4*)(state + (size_t)b * NT * KD))[tid];
        int r = tid >> 2, c = (tid & 3) * 4;
        float* dst = smS + r * 17 + c;
        dst[0] = v.x; dst[1] = v.y; dst[2] = v.z; dst[3] = v.w;
    }
    // per-lane projection weight columns (o = lane); die after phase 1
    float wqv[16], wkv[16], wvv[16];
    {
        const float4* q4 = (const float4*)(Wq + lane * KD);
        const float4* k4 = (const float4*)(Wk + lane * KD);
        const float4* v4 = (const float4*)(Wv + lane * KD);
        #pragma unroll
        for (int r4 = 0; r4 < 4; ++r4) {
            float4 a = q4[r4], c = k4[r4], d = v4[r4];
            wqv[r4*4+0]=a.x; wqv[r4*4+1]=a.y; wqv[r4*4+2]=a.z; wqv[r4*4+3]=a.w;
            wkv[r4*4+0]=c.x; wkv[r4*4+1]=c.y; wkv[r4*4+2]=c.z; wkv[r4*4+3]=c.w;
            wvv[r4*4+0]=d.x; wvv[r4*4+1]=d.y; wvv[r4*4+2]=d.z; wvv[r4*4+3]=d.w;
        }
    }
    const float bqo = bq[lane], bvo = bv[lane];
    __syncthreads();   // sync0: smS ready

    // ---- phase 1: Q (own row), Pk f32 + Pv f16 for ALL 128 rows ----
    {
        const float* sr = smS + iloc * 17;
        float aq = bqo;
        #pragma unroll
        for (int m = 0; m < 16; ++m) aq = fmaf(sr[m], wqv[m], aq);
        smQ[w * 68 + lane] = fmaxf(aq, 0.f) * 0.25f;   // 1/sqrt(16) folded
    }
    {
        // wave w covers rows w*16 .. w*16+15; Pv packed in pairs
        #pragma unroll
        for (int p = 0; p < 8; ++p) {
            int r0 = w * 16 + 2 * p;
            const float* s0 = smS + r0 * 17;
            const float* s1 = s0 + 17;
            float ak0 = 0.f, av0 = 0.f, ak1 = 0.f, av1 = 0.f;
            #pragma unroll
            for (int m = 0; m < 16; ++m) {
                float w_k = wkv[m], w_v = wvv[m];
                ak0 = fmaf(s0[m], w_k, ak0);
                av0 = fmaf(s0[m], w_v, av0);
                ak1 = fmaf(s1[m], w_k, ak1);
                av1 = fmaf(s1[m], w_v, av1);
            }
            smPk[(r0 + 0) * 68 + lane] = ak0;
            smPk[(r0 + 1) * 68 + lane] = ak1;
            *(unsigned*)(sm + L_PV + lane * 272 + w * 32 + p * 4) = cvt2h(av0, av1);
        }
    }
    __syncthreads();   // sync1: smQ / smPk / smPv ready

    // ---- per-row constants: relu(x+c) = c + max(x,-c); sum_j p_j = 1 ----
    float qA[16], mbeff[16], dotc = 0.f;
    {
        const float* qrow = smQ + w * 68 + h16;      // broadcast
        const float* pkI  = smPk + iloc * 68 + h16;  // broadcast
        const float4* bk4 = (const float4*)(bk + h16);
        #pragma unroll
        for (int q4 = 0; q4 < 4; ++q4) {
            float4 bb = bk4[q4];
            float bbv[4] = {bb.x, bb.y, bb.z, bb.w};
            #pragma unroll
            for (int kk = 0; kk < 4; ++kk) {
                int k = q4 * 4 + kk;
                float qv = qrow[k], pk = pkI[k];
                qA[k] = qv;
                mbeff[k] = pk - bbv[kk];                 // -c
                dotc = fmaf(qv, bbv[kk] - pk, dotc);     // + sum q*c
            }
        }
    }

    // ---- scores f32: lane (h,s) covers j = s + 16*jj ----
    float sc[8];
    #pragma unroll
    for (int jj = 0; jj < 8; ++jj) {
        const float4* pk = (const float4*)(smPk + (s + (jj << 4)) * 68 + h16);
        float a = dotc;
        #pragma unroll
        for (int q4 = 0; q4 < 4; ++q4) {
            float4 v = pk[q4];
            float f[4] = {v.x, v.y, v.z, v.w};
            #pragma unroll
            for (int kk = 0; kk < 4; ++kk) {
                int k = q4 * 4 + kk;
                a = fmaf(qA[k], fmaxf(f[kk], mbeff[k]), a);
            }
        }
        sc[jj] = a;
    }

    // ---- softmax over 128 j within the 16-lane head group ----
    float mx = sc[0];
    #pragma unroll
    for (int jj = 1; jj < 8; ++jj) mx = fmaxf(mx, sc[jj]);
    #pragma unroll
    for (int off = 1; off < 16; off <<= 1) mx = fmaxf(mx, __shfl_xor(mx, off));
    float l = 0.f;
    #pragma unroll
    for (int jj = 0; jj < 8; ++jj) { sc[jj] = __expf(sc[jj] - mx); l += sc[jj]; }
    #pragma unroll
    for (int off = 1; off < 16; off <<= 1) l += __shfl_xor(l, off);
    const float rl = 1.0f / l;
    {
        __fp16* prow = (__fp16*)(sm + L_P) + (w * 4 + h) * 136;
        #pragma unroll
        for (int jj = 0; jj < 8; ++jj) prow[(jj << 4) + s] = (__fp16)sc[jj];
    }
    asm volatile("s_waitcnt lgkmcnt(0)" ::: "memory");   // P row is intra-wave
    __builtin_amdgcn_sched_barrier(0);

    // ---- PV packed f16: x = -mbv + rl * sum p~ * max(v, mbv) ----
    float xA;
    {
        const __fp16 pvi = *((const __fp16*)(sm + L_PV) + lane * 136 + iloc);
        const float mbvf = (float)pvi - bvo;
        const __fp16 mbvh = (__fp16)mbvf;
        const f16x2 mbv2 = {mbvh, mbvh};
        const uint4* vrow = (const uint4*)(sm + L_PV + lane * 272);
        const uint4* prow = (const uint4*)(sm + L_P + (w * 4 + h) * 272);
        float acc = 0.f;
        #pragma unroll
        for (int u = 0; u < 16; ++u) {
            U4H8 v; v.u = vrow[u];
            U4H8 p; p.u = prow[u];
            #pragma unroll
            for (int t = 0; t < 4; ++t)
                acc = FDOT2(p.h[t], pkmax(v.h[t], mbv2), acc);
        }
        xA = fmaf(rl, acc, -(float)mbvh);
    }
    __syncthreads();   // sync2: all Pk/Pv/P reads done -> safe to alias Pk region

    // ---- X tile bf16 [16][104]: rows 0..7 live, rows 8..15 zero ----
    ((unsigned short*)(sm + L_X))[w * 104 + lane] = bf16rne(xA);
    if (tid < 128) {
        int r = tid >> 4, c = tid & 15;
        unsigned short* xr = (unsigned short*)(sm + L_X) + r * 104;
        xr[64 + c] = bf16rne(smS[(tile * 8 + r) * 17 + c]);
        xr[80 + c] = 0;
    }
    if (tid < 384) {   // zero rows 8..15 cols 0..95 (keeps MFMA A-frags finite)
        int r = 8 + tid / 48, c2 = (tid % 48) * 2;
        *(unsigned*)((unsigned short*)(sm + L_X) + r * 104 + c2) = 0u;
    }
    // W1 fragments for this wave's 2 col-tiles: load f32, cvt to bf16 (24 regs)
    uint4 w1f0[3], w1f1[3];
    #pragma unroll
    for (int ks = 0; ks < 3; ++ks) {
        int kb = ks * 32 + g * 8;
        if (kb < 80) {
            float4 a0 = *(const float4*)(W1 + n0 * 80 + kb);
            float4 a1 = *(const float4*)(W1 + n0 * 80 + kb + 4);
            float4 c0 = *(const float4*)(W1 + n1 * 80 + kb);
            float4 c1 = *(const float4*)(W1 + n1 * 80 + kb + 4);
            w1f0[ks].x = cvt2bf(a0.x, a0.y); w1f0[ks].y = cvt2bf(a0.z, a0.w);
            w1f0[ks].z = cvt2bf(a1.x, a1.y); w1f0[ks].w = cvt2bf(a1.z, a1.w);
            w1f1[ks].x = cvt2bf(c0.x, c0.y); w1f1[ks].y = cvt2bf(c0.z, c0.w);
            w1f1[ks].z = cvt2bf(c1.x, c1.y); w1f1[ks].w = cvt2bf(c1.z, c1.w);
        } else {
            w1f0[ks] = make_uint4(0, 0, 0, 0);
            w1f1[ks] = make_uint4(0, 0, 0, 0);
        }
    }
    __syncthreads();   // sync3: X ready

    // ---- layer 1 MFMA (K=96): wave w -> neurons w*32..w*32+31 ----
    {
        f32x4 a0 = {0.f, 0.f, 0.f, 0.f}, a1 = a0;
        #pragma unroll
        for (int ks = 0; ks < 3; ++ks) {
            U4B8 av; av.u = *(const uint4*)(sm + L_X + (lr * 104 + ks * 32 + g * 8) * 2);
            U4B8 b0; b0.u = w1f0[ks];
            U4B8 b1; b1.u = w1f1[ks];
            a0 = __builtin_amdgcn_mfma_f32_16x16x32_bf16(av.h, b0.h, a0, 0, 0, 0);
            a1 = __builtin_amdgcn_mfma_f32_16x16x32_bf16(av.h, b1.h, a1, 0, 0, 0);
        }
        const float bn0 = b1g[n0], bn1 = b1g[n1];
        #pragma unroll
        for (int qq = 0; qq < 4; ++qq) {
            *((unsigned short*)(sm + L_H1) + (4 * g + qq) * 264 + n0) =
                bf16rne(fmaxf(a0[qq] + bn0, 0.f));
            *((unsigned short*)(sm + L_H1) + (4 * g + qq) * 264 + n1) =
                bf16rne(fmaxf(a1[qq] + bn1, 0.f));
        }
    }
    __syncthreads();   // sync4

    // ---- layer 2 MFMA (K=256): stream W2 f32 with 1-ahead prefetch ----
    {
        const float* w2b0 = W2 + n0 * 256 + g * 8;
        const float* w2b1 = W2 + n1 * 256 + g * 8;
        float4 c00 = *(const float4*)(w2b0);
        float4 c01 = *(const float4*)(w2b0 + 4);
        float4 c10 = *(const float4*)(w2b1);
        float4 c11 = *(const float4*)(w2b1 + 4);
        f32x4 a0 = {0.f, 0.f, 0.f, 0.f}, a1 = a0;
        #pragma unroll 1
        for (int ks = 0; ks < 8; ++ks) {
            float4 nx00, nx01, nx10, nx11;
            if (ks < 7) {
                nx00 = *(const float4*)(w2b0 + (ks + 1) * 32);
                nx01 = *(const float4*)(w2b0 + (ks + 1) * 32 + 4);
                nx10 = *(const float4*)(w2b1 + (ks + 1) * 32);
                nx11 = *(const float4*)(w2b1 + (ks + 1) * 32 + 4);
            }
            U4B8 b0, b1;
            b0.u.x = cvt2bf(c00.x, c00.y); b0.u.y = cvt2bf(c00.z, c00.w);
            b0.u.z = cvt2bf(c01.x, c01.y); b0.u.w = cvt2bf(c01.z, c01.w);
            b1.u.x = cvt2bf(c10.x, c10.y); b1.u.y = cvt2bf(c10.z, c10.w);
            b1.u.z = cvt2bf(c11.x, c11.y); b1.u.w = cvt2bf(c11.z, c11.w);
            U4B8 av; av.u = *(const uint4*)(sm + L_H1 + (lr * 264 + ks * 32 + g * 8) * 2);
            a0 = __builtin_amdgcn_mfma_f32_16x16x32_bf16(av.h, b0.h, a0, 0, 0, 0);
            a1 = __builtin_amdgcn_mfma_f32_16x16x32_bf16(av.h, b1.h, a1, 0, 0, 0);
            c00 = nx00; c01 = nx01; c10 = nx10; c11 = nx11;
        }
        const float bn0 = b2g[n0], bn1 = b2g[n1];
        #pragma unroll
        for (int qq = 0; qq < 4; ++qq) {
            *((unsigned short*)(sm + L_H2) + (4 * g + qq) * 264 + n0) =
                bf16rne(fmaxf(a0[qq] + bn0, 0.f));
            *((unsigned short*)(sm + L_H2) + (4 * g + qq) * 264 + n1) =
                bf16rne(fmaxf(a1[qq] + bn1, 0.f));
        }
    }
    __syncthreads();   // sync5

    // ---- heads: 32 groups of 16 lanes (row m 0..7, output d 0..3) ----
    {
        const int g2 = tid >> 4, m = g2 >> 2, d = g2 & 3, cc = tid & 15;
        const float* wrow = (d < 2) ? (Wmu + d * 256) : (Wls + (d - 2) * 256);
        float hbuf[16];
        uint4 ha = *(const uint4*)(sm + L_H2 + (m * 264 + cc * 16) * 2);
        uint4 hb = *(const uint4*)(sm + L_H2 + (m * 264 + cc * 16 + 8) * 2);
        unpack8(ha, hbuf); unpack8(hb, hbuf + 8);
        float dd = 0.f;
        #pragma unroll
        for (int kk = 0; kk < 16; ++kk)
            dd = fmaf(hbuf[kk], wrow[cc * 16 + kk], dd);
        #pragma unroll
        for (int off = 1; off < 16; off <<= 1) dd += __shfl_xor(dd, off);
        float* hd = (float*)(sm + L_P);   // smP is dead: reuse as [8][4] buffer
        if (cc == 0) {
            float bias = (d < 2) ? bmu[d] : bls[d - 2];
            hd[m * 4 + d] = tanhf(dd + bias);
        }
    }
    __syncthreads();   // sync6
    if (tid < 8) {
        const float* hd = (const float*)(sm + L_P);
        const int m = tid;
        const int orow = b * NT + tile * 8 + m;
        float lp = 0.f;
        #pragma unroll
        for (int d = 0; d < 2; ++d) {
            float mu  = hd[m * 4 + d];
            float lsr = hd[m * 4 + 2 + d];
            float ls  = -20.f + 11.f * (lsr + 1.f);
            float e   = eps[orow * 2 + d];
            float z   = mu + __expf(ls) * e;
            float a   = tanhf(z);
            out[orow * 2 + d] = a;
            lp += -0.5f * e * e - ls - 0.91893853320467274f - __logf(1.f - a * a + 1e-7f);
        }
        out[NB * NT * 2 + orow] = lp;
    }
}

extern "C" void kernel_launch(void* const* d_in, const int* in_sizes, int n_in,
                              void* d_out, int out_size, void* d_ws, size_t ws_size,
                              hipStream_t stream) {
    const float* state = (const float*)d_in[0];
    const float* eps   = (const float*)d_in[1];
    const float* Wq    = (const float*)d_in[2];
    const float* bq    = (const float*)d_in[3];
    const float* Wk    = (const float*)d_in[4];
    const float* bk    = (const float*)d_in[5];
    const float* Wv    = (const float*)d_in[6];
    const float* bv    = (const float*)d_in[7];
    const float* W1    = (const float*)d_in[8];
    const float* b1    = (const float*)d_in[9];
    const float* W2    = (const float*)d_in[10];
    const float* b2    = (const float*)d_in[11];
    const float* Wmu   = (const float*)d_in[12];
    const float* bmu   = (const float*)d_in[13];
    const float* Wls   = (const float*)d_in[14];
    const float* bls   = (const float*)d_in[15];
    float* out = (float*)d_out;
    (void)d_ws; (void)ws_size;

    actor_kernel<<<NB * 16, 512, 0, stream>>>(
        state, eps, Wq, bq, Wk, bk, Wv, bv, W1, b1, W2, b2,
        Wmu, bmu, Wls, bls, out);
}

// Round 12
// 21.396 us; speedup vs baseline: 1.5369x; 1.5369x over previous
//
#include <hip/hip_runtime.h>
#include <math.h>

#define NB 32
#define NT 128
#define KD 16

// ws byte offsets
#define QG_OFF   0u          // f32 [4096][64]    1 MB   (relu(q)*0.25)
#define PKH_OFF  1048576u    // f16 [32][128][64] 512 KB
#define PVT_OFF  1572864u    // f16 [32][64][128] 512 KB (o-major)
#define W1P_OFF  2097152u    // bf16 MFMA frags [3*16][64] uint4, 48 KB
#define W2P_OFF  2146304u    // bf16 MFMA frags [8*16][64] uint4, 128 KB

typedef float f32x4 __attribute__((ext_vector_type(4)));
typedef short bf16x8 __attribute__((ext_vector_type(8)));
typedef __fp16 f16x2 __attribute__((ext_vector_type(2)));
union U4B8 { uint4 u; bf16x8 h; };
union U4H8 { uint4 u; f16x2 h[4]; };

// actor LDS map (47872 B)
#define L_PK 0        // f16 [128][72] = 18432 ; aliased by H1/H2 after syncA
#define L_PV 18432    // f16 [64][136] = 17408 (ends 35840)
#define L_P  35840    // f16 [32][136] = 8704  (ends 44544; head-buf later)
#define L_X  44544    // bf16 [16][104] = 3328 (fresh region, ends 47872)
#define L_TOT 47872
#define L_H1 0        // bf16 [16][264] = 8448
#define L_H2 8448     // ends 16896 <= 18432 (inside dead Pk)

__device__ __forceinline__ unsigned short bf16rne(float f) {
    unsigned u = __float_as_uint(f);
    return (unsigned short)((u + 0x7fffu + ((u >> 16) & 1u)) >> 16);
}
__device__ __forceinline__ void unpack8(uint4 u, float* f) {
    f[0] = __uint_as_float(u.x << 16); f[1] = __uint_as_float(u.x & 0xffff0000u);
    f[2] = __uint_as_float(u.y << 16); f[3] = __uint_as_float(u.y & 0xffff0000u);
    f[4] = __uint_as_float(u.z << 16); f[5] = __uint_as_float(u.z & 0xffff0000u);
    f[6] = __uint_as_float(u.w << 16); f[7] = __uint_as_float(u.w & 0xffff0000u);
}
__device__ __forceinline__ f16x2 pkmax(f16x2 a, f16x2 b) {
    f16x2 d;
    asm("v_pk_max_f16 %0, %1, %2" : "=v"(d) : "v"(a), "v"(b));
    return d;
}
#if __has_builtin(__builtin_amdgcn_fdot2)
#define FDOT2(a, b, c) __builtin_amdgcn_fdot2((a), (b), (c), false)
#else
#define FDOT2(a, b, c) ((c) + (float)(a)[0] * (float)(b)[0] + (float)(a)[1] * (float)(b)[1])
#endif

// ---------------- K0: projections + MFMA weight packing ----------------
__global__ __launch_bounds__(256) void prep_kernel(
    const float* __restrict__ state,
    const float* __restrict__ Wq, const float* __restrict__ bq,
    const float* __restrict__ Wk, const float* __restrict__ Wv,
    const float* __restrict__ W1, const float* __restrict__ W2,
    char* __restrict__ wsb)
{
    const int blk = blockIdx.x, tid = threadIdx.x;
    float* Qg = (float*)(wsb + QG_OFF);
    unsigned short* PkH = (unsigned short*)(wsb + PKH_OFF);
    unsigned short* PvT = (unsigned short*)(wsb + PVT_OFF);

    if (blk < 128) {
        __shared__ float Wl[3][64][17];
        __shared__ float Sl[32][17];
        const int b = blk >> 2, r0 = (blk & 3) * 32;
        for (int idx = tid; idx < 1024; idx += 256) {
            int o = idx >> 4, m = idx & 15;
            Wl[0][o][m] = Wq[idx];
            Wl[1][o][m] = Wk[idx];
            Wl[2][o][m] = Wv[idx];
        }
        for (int idx = tid; idx < 512; idx += 256)
            Sl[idx >> 4][idx & 15] = state[(size_t)(b * NT + r0) * KD + idx];
        __syncthreads();
        const int o = tid & 63, rr = tid >> 6;
        float wqv[16], wkv[16], wvv[16];
        #pragma unroll
        for (int m = 0; m < 16; ++m) {
            wqv[m] = Wl[0][o][m]; wkv[m] = Wl[1][o][m]; wvv[m] = Wl[2][o][m];
        }
        const float bqo = bq[o];
        for (int r = rr; r < 32; r += 4) {
            float aq = bqo, ak = 0.f, av = 0.f;
            #pragma unroll
            for (int m = 0; m < 16; ++m) {
                float s = Sl[r][m];
                aq = fmaf(s, wqv[m], aq);
                ak = fmaf(s, wkv[m], ak);
                av = fmaf(s, wvv[m], av);
            }
            int row = b * NT + r0 + r;
            Qg[row * 64 + o] = fmaxf(aq, 0.f) * 0.25f;   // 1/sqrt(16) folded
            __fp16 hk = (__fp16)ak;
            PkH[(size_t)b * 8192 + (r0 + r) * 64 + o] = *(unsigned short*)&hk;
            __fp16 hv = (__fp16)av;
            PvT[(size_t)b * 8192 + o * NT + (r0 + r)] = *(unsigned short*)&hv;
        }
    } else if (blk < 140) {
        int fi = (blk - 128) * 256 + tid;
        int l = fi & 63, rest = fi >> 6;
        int t = rest & 15, ks = rest >> 4;
        int n = t * 16 + (l & 15);
        int kb = ks * 32 + (l >> 4) * 8;
        unsigned short v[8];
        #pragma unroll
        for (int j = 0; j < 8; ++j) {
            int k = kb + j;
            v[j] = (k < 80) ? bf16rne(W1[n * 80 + k]) : (unsigned short)0;
        }
        uint4 u;
        u.x = (unsigned)v[0] | ((unsigned)v[1] << 16);
        u.y = (unsigned)v[2] | ((unsigned)v[3] << 16);
        u.z = (unsigned)v[4] | ((unsigned)v[5] << 16);
        u.w = (unsigned)v[6] | ((unsigned)v[7] << 16);
        ((uint4*)(wsb + W1P_OFF))[fi] = u;
    } else {
        int fi = (blk - 140) * 256 + tid;
        int l = fi & 63, rest = fi >> 6;
        int t = rest & 15, ks = rest >> 4;
        int n = t * 16 + (l & 15);
        int kb = ks * 32 + (l >> 4) * 8;
        unsigned short v[8];
        #pragma unroll
        for (int j = 0; j < 8; ++j) v[j] = bf16rne(W2[n * 256 + kb + j]);
        uint4 u;
        u.x = (unsigned)v[0] | ((unsigned)v[1] << 16);
        u.y = (unsigned)v[2] | ((unsigned)v[3] << 16);
        u.z = (unsigned)v[4] | ((unsigned)v[5] << 16);
        u.w = (unsigned)v[6] | ((unsigned)v[7] << 16);
        ((uint4*)(wsb + W2P_OFF))[fi] = u;
    }
}

// ---------------- K1: 8 rows/block, 512 blocks ----------------
__global__ __launch_bounds__(512, 4) void actor_kernel(
    const float* __restrict__ state, const float* __restrict__ eps,
    const float* __restrict__ bkg, const float* __restrict__ bvg,
    const float* __restrict__ b1g, const float* __restrict__ b2g,
    const float* __restrict__ Wmu, const float* __restrict__ bmu,
    const float* __restrict__ Wls, const float* __restrict__ bls,
    const char* __restrict__ wsb, float* __restrict__ out)
{
    __shared__ __align__(16) char sm[L_TOT];

    const int tid = threadIdx.x, w = tid >> 6, lane = tid & 63;
    const int bid = blockIdx.x;
    const int b    = (bid & 7) * 4 + ((bid >> 3) >> 4);  // batch -> fixed XCD
    const int tile = (bid >> 3) & 15;
    const int iloc = tile * 8 + w;
    const int row  = b * NT + iloc;
    const int h = lane >> 4, s = lane & 15, h16 = h << 4;
    const int g = h, lr = s;
    const int t0 = 2 * w;
    const int n0 = w * 32 + lr, n1 = n0 + 16;

    const float* Qg = (const float*)(wsb + QG_OFF);

    // ---- stage Pk f16 [128][72] and Pv f16 [64][136]; pre-zero X rows 8..15 ----
    {
        const uint4* srcK = (const uint4*)(wsb + PKH_OFF) + (size_t)b * 1024;
        #pragma unroll
        for (int it = 0; it < 2; ++it) {
            int idx = tid + it * 512;
            int r = idx >> 3, c = idx & 7;
            *(uint4*)(sm + L_PK + r * 144 + c * 16) = srcK[idx];
        }
        const uint4* srcV = (const uint4*)(wsb + PVT_OFF) + (size_t)b * 1024;
        #pragma unroll
        for (int it = 0; it < 2; ++it) {
            int idx = tid + it * 512;
            int o = idx >> 4, c = idx & 15;
            *(uint4*)(sm + L_PV + o * 272 + c * 16) = srcV[idx];
        }
        if (tid < 384) {   // zero X rows 8..15 cols 0..95 (fresh region: no hazard)
            int r = 8 + tid / 48, c2 = (tid % 48) * 2;
            *(unsigned*)((unsigned short*)(sm + L_X) + r * 104 + c2) = 0u;
        }
    }

    // ---- global prefetches (q, bk, state tail) overlap staging ----
    float qf[16], bkf[16];
    {
        const float4* qa  = (const float4*)(Qg + (size_t)row * 64 + h16);
        const float4* bk4 = (const float4*)(bkg + h16);
        #pragma unroll
        for (int q4 = 0; q4 < 4; ++q4) {
            float4 a = qa[q4], k4 = bk4[q4];
            qf[q4*4+0]=a.x; qf[q4*4+1]=a.y; qf[q4*4+2]=a.z; qf[q4*4+3]=a.w;
            bkf[q4*4+0]=k4.x; bkf[q4*4+1]=k4.y; bkf[q4*4+2]=k4.z; bkf[q4*4+3]=k4.w;
        }
    }
    const float bvo = bvg[lane];
    float stt = 0.f;
    if (tid < 128)
        stt = state[((size_t)b * NT + tile * 8 + (tid >> 4)) * KD + (tid & 15)];
    __syncthreads();   // sync1: Pk/Pv staged

    // ---- setup: q8/mb8 packed f16; dotc = sum q*c (c = bk - Pk_i) ----
    f16x2 q8[8], mb8[8];
    float dotc;
    {
        U4H8 p0, p1;
        p0.u = *(const uint4*)(sm + L_PK + iloc * 144 + h * 32);
        p1.u = *(const uint4*)(sm + L_PK + iloc * 144 + h * 32 + 16);
        #pragma unroll
        for (int t = 0; t < 4; ++t) {
            q8[t]     = __builtin_amdgcn_cvt_pkrtz(qf[2*t],   qf[2*t+1]);
            q8[4 + t] = __builtin_amdgcn_cvt_pkrtz(qf[8+2*t], qf[8+2*t+1]);
            f16x2 b0 = __builtin_amdgcn_cvt_pkrtz(bkf[2*t],   bkf[2*t+1]);
            f16x2 b1 = __builtin_amdgcn_cvt_pkrtz(bkf[8+2*t], bkf[8+2*t+1]);
            mb8[t]     = p0.h[t] - b0;   // -c = Pk_i - bk
            mb8[4 + t] = p1.h[t] - b1;
        }
        float d0 = 0.f, d1 = 0.f;
        #pragma unroll
        for (int t = 0; t < 4; ++t) {
            d0 = FDOT2(q8[t],     mb8[t],     d0);
            d1 = FDOT2(q8[4 + t], mb8[4 + t], d1);
        }
        dotc = -(d0 + d1);
    }

    // ---- scores: lane (h,s) covers j = s + 16*jj; f16 pkmax + dot2 ----
    float sc[8];
    #pragma unroll
    for (int jj = 0; jj < 8; ++jj) {
        const char* pr = sm + L_PK + (s + (jj << 4)) * 144 + h * 32;
        U4H8 v0, v1;
        v0.u = *(const uint4*)(pr);
        v1.u = *(const uint4*)(pr + 16);
        float aE = 0.f, aO = 0.f;
        #pragma unroll
        for (int t = 0; t < 4; ++t) {
            aE = FDOT2(q8[t],     pkmax(v0.h[t], mb8[t]),     aE);
            aO = FDOT2(q8[4 + t], pkmax(v1.h[t], mb8[4 + t]), aO);
        }
        sc[jj] = dotc + aE + aO;
    }

    // ---- softmax over 128 j within the 16-lane head group ----
    float mx = sc[0];
    #pragma unroll
    for (int jj = 1; jj < 8; ++jj) mx = fmaxf(mx, sc[jj]);
    #pragma unroll
    for (int off = 1; off < 16; off <<= 1) mx = fmaxf(mx, __shfl_xor(mx, off));
    float l = 0.f;
    #pragma unroll
    for (int jj = 0; jj < 8; ++jj) { sc[jj] = __expf(sc[jj] - mx); l += sc[jj]; }
    #pragma unroll
    for (int off = 1; off < 16; off <<= 1) l += __shfl_xor(l, off);
    const float rl = 1.0f / l;
    {
        __fp16* prow = (__fp16*)(sm + L_P) + (w * 4 + h) * 136;
        #pragma unroll
        for (int jj = 0; jj < 8; ++jj) prow[(jj << 4) + s] = (__fp16)sc[jj];
    }
    asm volatile("s_waitcnt lgkmcnt(0)" ::: "memory");   // P row is intra-wave
    __builtin_amdgcn_sched_barrier(0);

    // issue W1P B-frags now: latency hides under PV
    const uint4* W1P = (const uint4*)(wsb + W1P_OFF);
    uint4 w1f0[3], w1f1[3];
    #pragma unroll
    for (int ks = 0; ks < 3; ++ks) {
        w1f0[ks] = W1P[((ks << 4) + t0) * 64 + lane];
        w1f1[ks] = W1P[((ks << 4) + t0 + 1) * 64 + lane];
    }

    // ---- PV packed f16: x = -mbv + rl * sum p~ * max(v, mbv) ----
    float xA;
    {
        const __fp16 pvi = *((const __fp16*)(sm + L_PV) + lane * 136 + iloc);
        const float mbvf = (float)pvi - bvo;
        const __fp16 mbvh = (__fp16)mbvf;
        const f16x2 mbv2 = {mbvh, mbvh};
        const uint4* vrow = (const uint4*)(sm + L_PV + lane * 272);
        const uint4* prow = (const uint4*)(sm + L_P + (w * 4 + h) * 272);
        float acc = 0.f;
        #pragma unroll
        for (int u = 0; u < 16; ++u) {
            U4H8 v; v.u = vrow[u];
            U4H8 p; p.u = prow[u];
            #pragma unroll
            for (int t = 0; t < 4; ++t)
                acc = FDOT2(p.h[t], pkmax(v.h[t], mbv2), acc);
        }
        xA = fmaf(rl, acc, -(float)mbvh);
    }

    // ---- X tile (fresh region, no barrier needed before write) ----
    ((unsigned short*)(sm + L_X))[w * 104 + lane] = bf16rne(xA);
    if (tid < 128) {
        unsigned short* xr = (unsigned short*)(sm + L_X) + (tid >> 4) * 104;
        xr[64 + (tid & 15)] = bf16rne(stt);
        xr[80 + (tid & 15)] = 0;
    }
    __syncthreads();   // syncA: X ready; all Pk/Pv/P reads done -> alias safe

    // ---- layer 1 MFMA (K=96): wave w -> neurons w*32..w*32+31 ----
    const uint4* W2P = (const uint4*)(wsb + W2P_OFF);
    uint4 w2f0[4], w2f1[4];   // ks 0..3 prefetch (lands under L1)
    #pragma unroll
    for (int ks = 0; ks < 4; ++ks) {
        w2f0[ks] = W2P[((ks << 4) + t0) * 64 + lane];
        w2f1[ks] = W2P[((ks << 4) + t0 + 1) * 64 + lane];
    }
    {
        f32x4 a0 = {0.f, 0.f, 0.f, 0.f}, a1 = a0;
        #pragma unroll
        for (int ks = 0; ks < 3; ++ks) {
            U4B8 av; av.u = *(const uint4*)(sm + L_X + (lr * 104 + ks * 32 + g * 8) * 2);
            U4B8 b0; b0.u = w1f0[ks];
            U4B8 b1; b1.u = w1f1[ks];
            a0 = __builtin_amdgcn_mfma_f32_16x16x32_bf16(av.h, b0.h, a0, 0, 0, 0);
            a1 = __builtin_amdgcn_mfma_f32_16x16x32_bf16(av.h, b1.h, a1, 0, 0, 0);
        }
        const float bn0 = b1g[n0], bn1 = b1g[n1];
        #pragma unroll
        for (int qq = 0; qq < 4; ++qq) {
            *((unsigned short*)(sm + L_H1) + (4 * g + qq) * 264 + n0) =
                bf16rne(fmaxf(a0[qq] + bn0, 0.f));
            *((unsigned short*)(sm + L_H1) + (4 * g + qq) * 264 + n1) =
                bf16rne(fmaxf(a1[qq] + bn1, 0.f));
        }
    }
    __syncthreads();   // syncB

    // ---- layer 2 MFMA (K=256): ks0-3 from prefetch, ks4-7 from L2-hot ws ----
    {
        f32x4 a0 = {0.f, 0.f, 0.f, 0.f}, a1 = a0;
        #pragma unroll
        for (int ks = 0; ks < 4; ++ks) {
            U4B8 av; av.u = *(const uint4*)(sm + L_H1 + (lr * 264 + ks * 32 + g * 8) * 2);
            U4B8 b0; b0.u = w2f0[ks];
            U4B8 b1; b1.u = w2f1[ks];
            a0 = __builtin_amdgcn_mfma_f32_16x16x32_bf16(av.h, b0.h, a0, 0, 0, 0);
            a1 = __builtin_amdgcn_mfma_f32_16x16x32_bf16(av.h, b1.h, a1, 0, 0, 0);
        }
        #pragma unroll
        for (int ks = 4; ks < 8; ++ks) {
            U4B8 av; av.u = *(const uint4*)(sm + L_H1 + (lr * 264 + ks * 32 + g * 8) * 2);
            U4B8 b0; b0.u = W2P[((ks << 4) + t0) * 64 + lane];
            U4B8 b1; b1.u = W2P[((ks << 4) + t0 + 1) * 64 + lane];
            a0 = __builtin_amdgcn_mfma_f32_16x16x32_bf16(av.h, b0.h, a0, 0, 0, 0);
            a1 = __builtin_amdgcn_mfma_f32_16x16x32_bf16(av.h, b1.h, a1, 0, 0, 0);
        }
        const float bn0 = b2g[n0], bn1 = b2g[n1];
        #pragma unroll
        for (int qq = 0; qq < 4; ++qq) {
            *((unsigned short*)(sm + L_H2) + (4 * g + qq) * 264 + n0) =
                bf16rne(fmaxf(a0[qq] + bn0, 0.f));
            *((unsigned short*)(sm + L_H2) + (4 * g + qq) * 264 + n1) =
                bf16rne(fmaxf(a1[qq] + bn1, 0.f));
        }
    }
    __syncthreads();   // syncC

    // ---- heads: 32 groups of 16 lanes (row m 0..7, output d 0..3) ----
    {
        const int g2 = tid >> 4, m = g2 >> 2, d = g2 & 3, cc = tid & 15;
        const float* wrow = (d < 2) ? (Wmu + d * 256) : (Wls + (d - 2) * 256);
        float hbuf[16];
        uint4 ha = *(const uint4*)(sm + L_H2 + (m * 264 + cc * 16) * 2);
        uint4 hb = *(const uint4*)(sm + L_H2 + (m * 264 + cc * 16 + 8) * 2);
        unpack8(ha, hbuf); unpack8(hb, hbuf + 8);
        float dd = 0.f;
        #pragma unroll
        for (int kk = 0; kk < 16; ++kk)
            dd = fmaf(hbuf[kk], wrow[cc * 16 + kk], dd);
        #pragma unroll
        for (int off = 1; off < 16; off <<= 1) dd += __shfl_xor(dd, off);
        float* hd = (float*)(sm + L_P);   // P dead: reuse as [8][4] buffer
        if (cc == 0) {
            float bias = (d < 2) ? bmu[d] : bls[d - 2];
            hd[m * 4 + d] = tanhf(dd + bias);
        }
    }
    __syncthreads();   // syncD
    if (tid < 8) {
        const float* hd = (const float*)(sm + L_P);
        const int m = tid;
        const int orow = b * NT + tile * 8 + m;
        float lp = 0.f;
        #pragma unroll
        for (int d = 0; d < 2; ++d) {
            float mu  = hd[m * 4 + d];
            float lsr = hd[m * 4 + 2 + d];
            float ls  = -20.f + 11.f * (lsr + 1.f);
            float e   = eps[orow * 2 + d];
            float z   = mu + __expf(ls) * e;
            float a   = tanhf(z);
            out[orow * 2 + d] = a;
            lp += -0.5f * e * e - ls - 0.91893853320467274f - __logf(1.f - a * a + 1e-7f);
        }
        out[NB * NT * 2 + orow] = lp;
    }
}

extern "C" void kernel_launch(void* const* d_in, const int* in_sizes, int n_in,
                              void* d_out, int out_size, void* d_ws, size_t ws_size,
                              hipStream_t stream) {
    const float* state = (const float*)d_in[0];
    const float* eps   = (const float*)d_in[1];
    const float* Wq    = (const float*)d_in[2];
    const float* bq    = (const float*)d_in[3];
    const float* Wk    = (const float*)d_in[4];
    const float* bk    = (const float*)d_in[5];
    const float* Wv    = (const float*)d_in[6];
    const float* bv    = (const float*)d_in[7];
    const float* W1    = (const float*)d_in[8];
    const float* b1    = (const float*)d_in[9];
    const float* W2    = (const float*)d_in[10];
    const float* b2    = (const float*)d_in[11];
    const float* Wmu   = (const float*)d_in[12];
    const float* bmu   = (const float*)d_in[13];
    const float* Wls   = (const float*)d_in[14];
    const float* bls   = (const float*)d_in[15];
    float* out = (float*)d_out;
    char* wsb  = (char*)d_ws;

    prep_kernel<<<172, 256, 0, stream>>>(state, Wq, bq, Wk, Wv, W1, W2, wsb);
    actor_kernel<<<512, 512, 0, stream>>>(state, eps, bk, bv, b1, b2,
                                          Wmu, bmu, Wls, bls, wsb, out);
}